// Round 8
// baseline (20684.184 us; speedup 1.0000x reference)
//
#include <hip/hip_runtime.h>
#include <cstdint>
#include <cstddef>

// ---------- constants ----------
#define MM 4096
#define NSTEP 50
#define DD 100
#define HID 512
#define K0P 128          // 101 padded to 128
#define SIGC 0.4f
#define RC 0.05f
#define NWGP 256         // persistent workgroups (1 per CU), 512 threads each

typedef __bf16 bf16x8 __attribute__((ext_vector_type(8)));
typedef float  f32x4  __attribute__((ext_vector_type(4)));

typedef const __attribute__((address_space(1))) void* gvp;
typedef __attribute__((address_space(3))) void* lvp;

static __device__ __forceinline__ void load_lds16(const void* g, void* l) {
    __builtin_amdgcn_global_load_lds((gvp)g, (lvp)l, 16, 0, 0);
}

// ---------- weight prep ----------
__global__ void k_transpose(const float* __restrict__ in, __bf16* __restrict__ out,
                            int Ksrc, int Kpad, int N) {
    int idx = blockIdx.x * 256 + threadIdx.x;
    if (idx >= N * Kpad) return;
    int n = idx / Kpad, k = idx - n * Kpad;
    out[idx] = (k < Ksrc) ? (__bf16)in[k * N + n] : (__bf16)0.f;
}

__global__ void k_cast(const float* __restrict__ in, __bf16* __restrict__ out,
                       int Rsrc, int Rpad, int C) {
    int idx = blockIdx.x * 256 + threadIdx.x;
    if (idx >= Rpad * C) return;
    int r = idx / C;
    out[idx] = (r < Rsrc) ? (__bf16)in[idx] : (__bf16)0.f;
}

// ---------- 4-WG group barrier (monotone generation, agent scope) ----------
__device__ __forceinline__ void groupbar(int* cnt, int* gen, int& g) {
    __syncthreads();
    if (threadIdx.x == 0) {
        int prev = __hip_atomic_fetch_add(cnt, 1, __ATOMIC_ACQ_REL,
                                          __HIP_MEMORY_SCOPE_AGENT);
        if (prev == 3) {
            __hip_atomic_store(cnt, 0, __ATOMIC_RELAXED, __HIP_MEMORY_SCOPE_AGENT);
            __hip_atomic_store(gen, g + 1, __ATOMIC_RELEASE, __HIP_MEMORY_SCOPE_AGENT);
        } else {
            while (__hip_atomic_load(gen, __ATOMIC_ACQUIRE,
                                     __HIP_MEMORY_SCOPE_AGENT) < g + 1)
                __builtin_amdgcn_s_sleep(1);
        }
        g = g + 1;
    }
    __syncthreads();
}

// ---------- one GEMM phase (round-6-verified math, 512-thread layout) ----------
// BM=64, BN=128, BK=64, 8 waves (2x4), wave tile 32x32, double-buffered LDS.
// EPI 0: fwd layer: v+=bias; sin->out0, cos->out1
// EPI 1: bwd layer: v*=cmul; ->out0
// EPI 2: fwd L3: v+=bias; cos*W4->out0; Y[m] += sin*W4 (atomic)
// EPI 3: bwd L0 + Euler/terminal fused; returns resid (lane0 of each wave)
template <int EPI>
__device__ __forceinline__ float phase(
    int tid, int colBlk, int rowBlk, char* lds,
    const __bf16* __restrict__ A, const __bf16* __restrict__ Bm,
    const float* __restrict__ bias, const __bf16* __restrict__ cmul,
    __bf16* __restrict__ out0, __bf16* __restrict__ out1,
    const float* __restrict__ W4, float* __restrict__ Y,
    const float* __restrict__ t, const float* __restrict__ Wb,
    float* __restrict__ X, float* __restrict__ Ytil,
    __bf16* __restrict__ tXout, float b4v,
    int n, int K, int Nout) {

    const int wave = tid >> 6, lane = tid & 63;
    const int lr = lane & 15, lg = lane >> 4;
    const int wr = (wave >> 2) * 32;   // 2 wave-rows
    const int wc = (wave & 3) * 32;    // 4 wave-cols

    f32x4 acc4[2][2] = {};

    // staging: A 1 issue (8KB), B 2 issues (16KB) of 16B/thread
    const int aRow = tid >> 3;
    const int aG = (tid & 7) ^ (aRow & 7);
    int bRow[2], bG[2];
    #pragma unroll
    for (int it = 0; it < 2; it++) {
        int chunk = it * 512 + tid;
        bRow[it] = chunk >> 3;
        bG[it] = (chunk & 7) ^ (bRow[it] & 7);
    }

    const int NK = K >> 6;

    // buf0: A@0, buf1: A@8192; B buf0 @16384, B buf1 @32768
    #define STAGE(kb, buf)                                                         \
        {   char* Ad_ = lds + (buf) * 8192 + wave * 1024;                          \
            char* Bd_ = lds + 16384 + (buf) * 16384 + wave * 1024;                 \
            int k0_ = (kb) << 6;                                                   \
            load_lds16(A + (size_t)(rowBlk + aRow) * K + k0_ + aG * 8, Ad_);       \
            _Pragma("unroll")                                                      \
            for (int it = 0; it < 2; it++)                                         \
                load_lds16(Bm + (size_t)(colBlk + bRow[it]) * K + k0_ + bG[it] * 8,\
                           Bd_ + it * 8192); }

    STAGE(0, 0)
    __syncthreads();

    for (int kb = 0; kb < NK; kb++) {
        const int cur = kb & 1;
        if (kb + 1 < NK) STAGE(kb + 1, cur ^ 1)
        const char* As = lds + cur * 8192;
        const char* Bs = lds + 16384 + cur * 16384;
        #pragma unroll
        for (int ks = 0; ks < 2; ks++) {
            bf16x8 aF[2], bF[2];
            #pragma unroll
            for (int mi = 0; mi < 2; mi++) {
                int row = wr + mi * 16 + lr;
                int p = (ks * 4 + lg) ^ (row & 7);
                aF[mi] = *(const bf16x8*)(As + row * 128 + p * 16);
            }
            #pragma unroll
            for (int nj = 0; nj < 2; nj++) {
                int row = wc + nj * 16 + lr;
                int p = (ks * 4 + lg) ^ (row & 7);
                bF[nj] = *(const bf16x8*)(Bs + row * 128 + p * 16);
            }
            #pragma unroll
            for (int mi = 0; mi < 2; mi++)
                #pragma unroll
                for (int nj = 0; nj < 2; nj++)
                    acc4[mi][nj] = __builtin_amdgcn_mfma_f32_16x16x32_bf16(
                        aF[mi], bF[nj], acc4[mi][nj], 0, 0, 0);
        }
        __syncthreads();
    }
    #undef STAGE

    if (EPI == 0) {
        #pragma unroll
        for (int nj = 0; nj < 2; nj++) {
            int col = colBlk + wc + nj * 16 + lr;
            float bv = bias[col];
            #pragma unroll
            for (int mi = 0; mi < 2; mi++)
                #pragma unroll
                for (int r = 0; r < 4; r++) {
                    int row = rowBlk + wr + mi * 16 + lg * 4 + r;
                    float v = acc4[mi][nj][r] + bv;
                    float s, c;
                    __sincosf(v, &s, &c);
                    out0[(size_t)row * Nout + col] = (__bf16)s;
                    out1[(size_t)row * Nout + col] = (__bf16)c;
                }
        }
    } else if (EPI == 1) {
        #pragma unroll
        for (int nj = 0; nj < 2; nj++) {
            int col = colBlk + wc + nj * 16 + lr;
            #pragma unroll
            for (int mi = 0; mi < 2; mi++)
                #pragma unroll
                for (int r = 0; r < 4; r++) {
                    int row = rowBlk + wr + mi * 16 + lg * 4 + r;
                    float v = acc4[mi][nj][r] * (float)cmul[(size_t)row * Nout + col];
                    out0[(size_t)row * Nout + col] = (__bf16)v;
                }
        }
    } else if (EPI == 2) {
        float ysum[2][4] = {};
        #pragma unroll
        for (int nj = 0; nj < 2; nj++) {
            int col = colBlk + wc + nj * 16 + lr;
            float bv = bias[col];
            float w4 = W4[col];
            #pragma unroll
            for (int mi = 0; mi < 2; mi++)
                #pragma unroll
                for (int r = 0; r < 4; r++) {
                    int row = rowBlk + wr + mi * 16 + lg * 4 + r;
                    float v = acc4[mi][nj][r] + bv;
                    float s, c;
                    __sincosf(v, &s, &c);
                    out0[(size_t)row * Nout + col] = (__bf16)(c * w4);
                    ysum[mi][r] += s * w4;
                }
        }
        #pragma unroll
        for (int mi = 0; mi < 2; mi++)
            #pragma unroll
            for (int r = 0; r < 4; r++) {
                float v = ysum[mi][r];
                v += __shfl_xor(v, 1);
                v += __shfl_xor(v, 2);
                v += __shfl_xor(v, 4);
                v += __shfl_xor(v, 8);
                if (lr == 0) {
                    int row = rowBlk + wr + mi * 16 + lg * 4 + r;
                    atomicAdd(&Y[row], v);
                }
            }
    } else {  // EPI == 3
        __syncthreads();
        float* Zs = (float*)lds;   // [64][132] f32 = 33792 B
        #pragma unroll
        for (int nj = 0; nj < 2; nj++) {
            int col = wc + nj * 16 + lr;
            #pragma unroll
            for (int mi = 0; mi < 2; mi++)
                #pragma unroll
                for (int r = 0; r < 4; r++) {
                    int rl = wr + mi * 16 + lg * 4 + r;
                    Zs[rl * 132 + col] = acc4[mi][nj][r];
                }
        }
        __syncthreads();
        float resid = 0.f;
        #pragma unroll
        for (int rl = 0; rl < 8; rl++) {
            int lrow = wave * 8 + rl;
            int grow = rowBlk + lrow;
            float t0v = 0.f, t1v = 0.f;
            if (n < NSTEP) {
                t0v = t[grow * (NSTEP + 1) + n];
                t1v = t[grow * (NSTEP + 1) + n + 1];
            }
            float pXZ = 0.f, pZs = 0.f, gX = 0.f, sD = 0.f;
            #pragma unroll
            for (int ii = 0; ii < 2; ii++) {
                int d = lane + ii * 64;
                if (d < DD) {
                    float x0 = X[grow * DD + d];
                    float z = Zs[lrow * 132 + 1 + d];
                    if (n < NSTEP) {
                        float dWv = Wb[((size_t)grow * (NSTEP + 1) + n + 1) * DD + d] -
                                    Wb[((size_t)grow * (NSTEP + 1) + n) * DD + d];
                        float s = SIGC * x0 * dWv;
                        pXZ += x0 * z;
                        pZs += z * s;
                        float x1 = x0 + s;
                        X[grow * DD + d] = x1;
                        tXout[(size_t)grow * K0P + 1 + d] = (__bf16)x1;
                    } else {
                        gX += x0 * x0;
                        float e = z - 2.f * x0;
                        sD += e * e;
                    }
                }
            }
            for (int off = 32; off; off >>= 1) {
                pXZ += __shfl_down(pXZ, off);
                pZs += __shfl_down(pZs, off);
                gX  += __shfl_down(gX, off);
                sD  += __shfl_down(sD, off);
            }
            if (lane == 0) {
                float y0 = Y[grow];
                if (n >= 1) {
                    float dd = y0 - Ytil[grow];
                    resid += dd * dd;
                }
                if (n < NSTEP) {
                    float phi = RC * (y0 - pXZ);
                    Ytil[grow] = y0 + phi * (t1v - t0v) + pZs;
                    tXout[(size_t)grow * K0P] = (__bf16)t1v;
                    Y[grow] = b4v;
                } else {
                    float e = y0 - gX;
                    resid += e * e + sD;
                }
            }
        }
        return resid;
    }
    return 0.f;
}

// ---------- persistent megakernel (group-synced) ----------
__global__ __launch_bounds__(512, 1) void mega(
    const float* __restrict__ t, const float* __restrict__ W,
    const float* __restrict__ Xi,
    const __bf16* __restrict__ wt0, const __bf16* __restrict__ wt1,
    const __bf16* __restrict__ wt2, const __bf16* __restrict__ wt3,
    const __bf16* __restrict__ wd0, const __bf16* __restrict__ wd1,
    const __bf16* __restrict__ wd2, const __bf16* __restrict__ wd3,
    const float* __restrict__ b0, const float* __restrict__ b1,
    const float* __restrict__ b2, const float* __restrict__ b3,
    const float* __restrict__ W4, const float* __restrict__ b4,
    __bf16* __restrict__ tX,
    __bf16* __restrict__ a0, __bf16* __restrict__ a1, __bf16* __restrict__ a2,
    __bf16* __restrict__ c0, __bf16* __restrict__ c1, __bf16* __restrict__ c2,
    __bf16* __restrict__ gza, __bf16* __restrict__ gzb,
    float* __restrict__ X, float* __restrict__ Y, float* __restrict__ Ytil,
    float* __restrict__ acc, int* barr) {

    __shared__ __align__(16) char lds[49152];
    const int tid = threadIdx.x;
    const int wg = blockIdx.x;
    const int group  = wg & 63;        // same-XCD members: wg, wg+64, wg+128, wg+192
    const int member = wg >> 6;
    const int colBlk = member * 128;
    const int rowBlk = group * 64;
    int* cnt = barr + group * 64;      // one 256B line per group
    int* gen = cnt + 32;
    int g = 0;
    const float b4v = b4[0];

    // ---- init: member m inits rows [rowBlk + m*16, +16) (in-group ownership) ----
    {
        int row = rowBlk + member * 16 + (tid >> 5);
        int c4 = (tid & 31) * 4;
        #pragma unroll
        for (int i = 0; i < 4; i++) {
            int col = c4 + i;
            float v;
            if (col == 0) v = t[row * (NSTEP + 1)];
            else if (col <= DD) v = Xi[col - 1];
            else v = 0.f;
            tX[(size_t)row * K0P + col] = (__bf16)v;
            if (col >= 1 && col <= DD) X[row * DD + col - 1] = v;
        }
        if ((tid & 31) == 0) Y[row] = b4v;
    }
    float resid = 0.f;
    groupbar(cnt, gen, g);

    for (int n = 0; n <= NSTEP; n++) {
        phase<0>(tid, colBlk, rowBlk, lds, tX, wt0, b0, nullptr, a0, c0,
                 nullptr, nullptr, nullptr, nullptr, nullptr, nullptr, nullptr,
                 0.f, n, K0P, HID);
        groupbar(cnt, gen, g);
        phase<0>(tid, colBlk, rowBlk, lds, a0, wt1, b1, nullptr, a1, c1,
                 nullptr, nullptr, nullptr, nullptr, nullptr, nullptr, nullptr,
                 0.f, n, HID, HID);
        groupbar(cnt, gen, g);
        phase<0>(tid, colBlk, rowBlk, lds, a1, wt2, b2, nullptr, a2, c2,
                 nullptr, nullptr, nullptr, nullptr, nullptr, nullptr, nullptr,
                 0.f, n, HID, HID);
        groupbar(cnt, gen, g);
        phase<2>(tid, colBlk, rowBlk, lds, a2, wt3, b3, nullptr, gza, nullptr,
                 W4, Y, nullptr, nullptr, nullptr, nullptr, nullptr,
                 0.f, n, HID, HID);
        groupbar(cnt, gen, g);
        phase<1>(tid, colBlk, rowBlk, lds, gza, wd3, nullptr, c2, gzb, nullptr,
                 nullptr, nullptr, nullptr, nullptr, nullptr, nullptr, nullptr,
                 0.f, n, HID, HID);
        groupbar(cnt, gen, g);
        phase<1>(tid, colBlk, rowBlk, lds, gzb, wd2, nullptr, c1, gza, nullptr,
                 nullptr, nullptr, nullptr, nullptr, nullptr, nullptr, nullptr,
                 0.f, n, HID, HID);
        groupbar(cnt, gen, g);
        phase<1>(tid, colBlk, rowBlk, lds, gza, wd1, nullptr, c0, gzb, nullptr,
                 nullptr, nullptr, nullptr, nullptr, nullptr, nullptr, nullptr,
                 0.f, n, HID, HID);
        groupbar(cnt, gen, g);
        if (member == 0)
            resid += phase<3>(tid, 0, rowBlk, lds, gzb, wd0, nullptr, nullptr,
                              nullptr, nullptr, nullptr, Y, t, W, X, Ytil, tX,
                              b4v, n, HID, K0P);
        groupbar(cnt, gen, g);
    }

    if (member == 0 && (tid & 63) == 0) atomicAdd(acc, resid);
}

__global__ void k_final(const float* __restrict__ acc, float* __restrict__ out) {
    out[0] = acc[0] / (float)MM;
}

// ---------- host ----------
extern "C" void kernel_launch(void* const* d_in, const int* in_sizes, int n_in,
                              void* d_out, int out_size, void* d_ws, size_t ws_size,
                              hipStream_t stream) {
    (void)in_sizes; (void)n_in; (void)out_size; (void)ws_size;
    const float* t  = (const float*)d_in[0];
    const float* W  = (const float*)d_in[1];
    const float* Xi = (const float*)d_in[2];
    const float* Wm[5];
    const float* bb[5];
    for (int i = 0; i < 5; i++) {
        Wm[i] = (const float*)d_in[3 + 2 * i];
        bb[i] = (const float*)d_in[4 + 2 * i];
    }

    char* p = (char*)d_ws;
    auto alloc = [&](size_t bytes) -> void* {
        void* r = (void*)p;
        p += (bytes + 255) & ~(size_t)255;
        return r;
    };

    __bf16* wt[4];
    wt[0] = (__bf16*)alloc((size_t)HID * K0P * 2);
    for (int i = 1; i < 4; i++) wt[i] = (__bf16*)alloc((size_t)HID * HID * 2);
    __bf16* wd[4];
    wd[0] = (__bf16*)alloc((size_t)K0P * HID * 2);
    for (int i = 1; i < 4; i++) wd[i] = (__bf16*)alloc((size_t)HID * HID * 2);
    __bf16* tX = (__bf16*)alloc((size_t)MM * K0P * 2);
    __bf16 *a[3], *c[3];
    for (int i = 0; i < 3; i++) a[i] = (__bf16*)alloc((size_t)MM * HID * 2);
    for (int i = 0; i < 3; i++) c[i] = (__bf16*)alloc((size_t)MM * HID * 2);
    __bf16* gza = (__bf16*)alloc((size_t)MM * HID * 2);
    __bf16* gzb = (__bf16*)alloc((size_t)MM * HID * 2);
    float* X    = (float*)alloc((size_t)MM * DD * 4);
    float* Y    = (float*)alloc((size_t)MM * 4);
    float* Ytil = (float*)alloc((size_t)MM * 4);
    float* acc  = (float*)alloc(256);
    int*   barr = (int*)alloc(16384);   // 64 groups x 256B

    hipMemsetAsync(acc, 0, 256, stream);
    hipMemsetAsync(barr, 0, 16384, stream);

    // weight prep
    k_transpose<<<(HID * K0P + 255) / 256, 256, 0, stream>>>(Wm[0], wt[0], 101, K0P, HID);
    for (int i = 1; i < 4; i++)
        k_transpose<<<(HID * HID + 255) / 256, 256, 0, stream>>>(Wm[i], wt[i], HID, HID, HID);
    k_cast<<<(K0P * HID + 255) / 256, 256, 0, stream>>>(Wm[0], wd[0], 101, K0P, HID);
    for (int i = 1; i < 4; i++)
        k_cast<<<(HID * HID + 255) / 256, 256, 0, stream>>>(Wm[i], wd[i], HID, HID, HID);

    mega<<<dim3(NWGP), dim3(512), 0, stream>>>(
        t, W, Xi,
        wt[0], wt[1], wt[2], wt[3],
        wd[0], wd[1], wd[2], wd[3],
        bb[0], bb[1], bb[2], bb[3],
        Wm[4], bb[4],
        tX, a[0], a[1], a[2], c[0], c[1], c[2], gza, gzb,
        X, Y, Ytil, acc, barr);

    k_final<<<1, 1, 0, stream>>>(acc, (float*)d_out);
}

// Round 9
// 13151.852 us; speedup vs baseline: 1.5727x; 1.5727x over previous
//
#include <hip/hip_runtime.h>
#include <cstdint>
#include <cstddef>

#define MM 4096
#define NSTEP 50
#define DD 100
#define HID 512
#define K0P 128
#define SIGC 0.4f
#define RC 0.05f
#define BMR 32
#define NWG (MM / BMR)   // 128 WGs, one per CU (LDS-capped), fully independent

typedef __bf16 bf16x8 __attribute__((ext_vector_type(8)));
typedef float  f32x4  __attribute__((ext_vector_type(4)));
union Pack4 { __bf16 h[4]; uint2 u2; };

typedef const __attribute__((address_space(1))) void* gvp;
typedef __attribute__((address_space(3))) void* lvp;
static __device__ __forceinline__ void load_lds16(const void* g, void* l) {
    __builtin_amdgcn_global_load_lds((gvp)g, (lvp)l, 16, 0, 0);
}

// ---------- weight prep (round-6 verbatim) ----------
__global__ void k_transpose(const float* __restrict__ in, __bf16* __restrict__ out,
                            int Ksrc, int Kpad, int N) {
    int idx = blockIdx.x * 256 + threadIdx.x;
    if (idx >= N * Kpad) return;
    int n = idx / Kpad, k = idx - n * Kpad;
    out[idx] = (k < Ksrc) ? (__bf16)in[k * N + n] : (__bf16)0.f;
}

__global__ void k_cast(const float* __restrict__ in, __bf16* __restrict__ out,
                       int Rsrc, int Rpad, int C) {
    int idx = blockIdx.x * 256 + threadIdx.x;
    if (idx >= Rpad * C) return;
    int r = idx / C;
    out[idx] = (r < Rsrc) ? (__bf16)in[idx] : (__bf16)0.f;
}

// ---------- tX writer: swizzled bf16 [32][128] in LDS (round-4 pair-proven) ----------
__device__ __forceinline__ void write_tX(char* T, int m, int dg, int d0,
                                         const float* x, float tval) {
    #pragma unroll
    for (int i = 0; i < 7; i++) {
        int col = 1 + d0 + i;
        int po = m * 256 + (((col >> 3) ^ (m & 7)) << 4) + (col & 7) * 2;
        *(__bf16*)(T + po) = (__bf16)x[i];
    }
    if (dg == 0) {
        int po = m * 256 + ((m & 7) << 4);
        *(__bf16*)(T + po) = (__bf16)tval;
    }
    if (dg == 15) {
        #pragma unroll
        for (int c = 113; c < 128; c++) {
            int po = m * 256 + (((c >> 3) ^ (m & 7)) << 4) + (c & 7) * 2;
            *(__bf16*)(T + po) = (__bf16)0.f;
        }
    }
}

// ---------- one layer pass: C[m][n] = sum_k A[m][k]*B[n][k], row-local ----------
// A: LDS swizzled [32][K]; B: global weights streamed in [NBLK][64] chunks,
// double-buffered via global_load_lds (round-6 discipline: STAGE(q+1); compute(q); barrier).
// Swapped-operand MFMA (round-4 convention): mfma(B_frag, A_frag) -> C col=m(lr), row=n(lg*4+r).
// EPI 0: fwd: v+=bias; sin->Rout (swizzled), cos->stash regs
// EPI 1: fwd L3: v+=bias; cos*W4->Rout; u partials -> u_lds atomics
// EPI 2: bwd: v*stash -> Rout
// EPI 3: bwd L0: v f32 -> Rout as Z [32][132] f32
template <int K, int NBLK, int NJB, int ASTR, int EPI>
__device__ __forceinline__ void phaseP(
    int tid, const __bf16* __restrict__ Bw,
    const char* __restrict__ Rin, char* __restrict__ Rout,
    char* __restrict__ Bb,
    const float* __restrict__ bias, const float* __restrict__ W4,
    Pack4 (&stash)[2][4], float* __restrict__ u_lds) {

    constexpr int NKB = K / 64;        // k-chunks per j-block
    constexpr int NJ  = NBLK / 64;     // col-frags per wave (4 or 2)
    constexpr int I   = (NBLK * 128) / 8192;  // stage instrs/thread (4 or 2)
    constexpr int NQ  = NJB * NKB;

    const int wave = tid >> 6, lane = tid & 63;
    const int lr = lane & 15, lg = lane >> 4;
    const int wr = (wave >> 2) * 16;   // 2 wave-rows of 16
    const int wq = wave & 3;           // 4 wave-cols
    const int am = wr + lr;            // this thread's sample row

    int bRow[I], bG[I];
    #pragma unroll
    for (int it = 0; it < I; it++) {
        int c16 = it * 512 + tid;
        bRow[it] = c16 >> 3;
        bG[it] = (c16 & 7) ^ (bRow[it] & 7);
    }

    #define STG(q)                                                               \
        {   int jb_ = (q) / NKB, kb_ = (q) - jb_ * NKB;                          \
            char* dst_ = Bb + ((q) & 1) * 32768 + wave * 1024;                   \
            _Pragma("unroll")                                                    \
            for (int it = 0; it < I; it++)                                       \
                load_lds16(Bw + (size_t)(jb_ * NBLK + bRow[it]) * K + kb_ * 64   \
                               + bG[it] * 8, dst_ + it * 8192); }

    STG(0)
    __syncthreads();

    float up = 0.f;
    #pragma unroll
    for (int jb = 0; jb < NJB; jb++) {
        f32x4 acc[NJ] = {};
        for (int kb = 0; kb < NKB; kb++) {
            const int q = jb * NKB + kb;
            if (q + 1 < NQ) STG(q + 1)
            const char* slot = Bb + (q & 1) * 32768;
            #pragma unroll
            for (int ks = 0; ks < 2; ks++) {
                int kch = kb * 8 + ks * 4 + lg;
                bf16x8 aF = *(const bf16x8*)(Rin + am * ASTR + ((kch ^ (am & 7)) << 4));
                #pragma unroll
                for (int nj = 0; nj < NJ; nj++) {
                    int nl = wq * (NBLK / 4) + nj * 16 + lr;
                    bf16x8 bF = *(const bf16x8*)(slot + nl * 128 +
                                 (((ks * 4 + lg) ^ (nl & 7)) << 4));
                    acc[nj] = __builtin_amdgcn_mfma_f32_16x16x32_bf16(
                        bF, aF, acc[nj], 0, 0, 0);
                }
            }
            __syncthreads();
        }
        // epilogue for this j-block
        #pragma unroll
        for (int nj = 0; nj < NJ; nj++) {
            const int n0 = jb * NBLK + wq * (NBLK / 4) + nj * 16 + lg * 4;
            if (EPI == 3) {
                *(f32x4*)((float*)Rout + am * 132 + n0) = acc[nj];
            } else {
                const int po = am * 1024 + (((n0 >> 3) ^ (am & 7)) << 4) + (n0 & 7) * 2;
                if (EPI == 0) {
                    f32x4 bv = *(const f32x4*)(bias + n0);
                    Pack4 ps, pc;
                    #pragma unroll
                    for (int r = 0; r < 4; r++) {
                        float s, c;
                        __sincosf(acc[nj][r] + bv[r], &s, &c);
                        ps.h[r] = (__bf16)s;
                        pc.h[r] = (__bf16)c;
                    }
                    *(uint2*)(Rout + po) = ps.u2;
                    stash[jb][nj] = pc;
                } else if (EPI == 1) {
                    f32x4 bv = *(const f32x4*)(bias + n0);
                    f32x4 wv = *(const f32x4*)(W4 + n0);
                    Pack4 pg;
                    #pragma unroll
                    for (int r = 0; r < 4; r++) {
                        float s, c;
                        __sincosf(acc[nj][r] + bv[r], &s, &c);
                        up += s * wv[r];
                        pg.h[r] = (__bf16)(c * wv[r]);
                    }
                    *(uint2*)(Rout + po) = pg.u2;
                } else {  // EPI == 2
                    Pack4 pm = stash[jb][nj];
                    Pack4 pg;
                    #pragma unroll
                    for (int r = 0; r < 4; r++)
                        pg.h[r] = (__bf16)(acc[nj][r] * (float)pm.h[r]);
                    *(uint2*)(Rout + po) = pg.u2;
                }
            }
        }
    }
    #undef STG

    if (EPI == 1) {
        up += __shfl_xor(up, 16);
        up += __shfl_xor(up, 32);
        if (lg == 0) atomicAdd(&u_lds[am], up);
    }
}

// ---------- the megakernel: 1 launch, zero inter-WG sync ----------
__global__ __launch_bounds__(512, 1) void mega(
    const float* __restrict__ t, const float* __restrict__ W,
    const float* __restrict__ Xi,
    const __bf16* __restrict__ wt0, const __bf16* __restrict__ wt1,
    const __bf16* __restrict__ wt2, const __bf16* __restrict__ wt3,
    const __bf16* __restrict__ wd0, const __bf16* __restrict__ wd1,
    const __bf16* __restrict__ wd2, const __bf16* __restrict__ wd3,
    const float* __restrict__ b0, const float* __restrict__ b1,
    const float* __restrict__ b2, const float* __restrict__ b3,
    const float* __restrict__ W4, const float* __restrict__ b4,
    float* __restrict__ accG) {

    extern __shared__ char lds[];
    char*  R0    = lds;                       // 32KB act slot
    char*  R1    = lds + 32768;               // 32KB act slot; tX at [0,8K), Z at +8448
    char*  Bb    = lds + 65536;               // 2 x 32KB B chunk slots
    float* u_lds = (float*)(lds + 131072);    // 32 f32 + 8 f32 red
    float* red   = u_lds + 32;
    float* Zf    = (float*)(R1 + 8448);       // [32][132] f32

    const int tid = threadIdx.x;
    const int wgrow = blockIdx.x * BMR;
    const int em = tid >> 4, edg = tid & 15, ed0 = edg * 7;
    const int grow = wgrow + em;
    const float b4v = b4[0];

    float x[7];
    #pragma unroll
    for (int i = 0; i < 7; i++) {
        int d = ed0 + i;
        x[i] = (d < DD) ? Xi[d] : 0.f;
    }
    float ytil = 0.f, resid = 0.f;
    Pack4 st0[2][4], st1[2][4], st2[2][4], stD[2][4];

    write_tX(R1, em, edg, ed0, x, t[grow * (NSTEP + 1)]);
    __syncthreads();

    for (int n = 0; n <= NSTEP; n++) {
        // forward
        phaseP<128, 256, 2, 256, 0>(tid, wt0, R1, R0, Bb, b0, nullptr, st0, u_lds);
        __syncthreads();
        phaseP<512, 256, 2, 1024, 0>(tid, wt1, R0, R1, Bb, b1, nullptr, st1, u_lds);
        __syncthreads();
        phaseP<512, 256, 2, 1024, 0>(tid, wt2, R1, R0, Bb, b2, nullptr, st2, u_lds);
        __syncthreads();
        if (tid < 32) u_lds[tid] = 0.f;
        __syncthreads();
        phaseP<512, 256, 2, 1024, 1>(tid, wt3, R0, R1, Bb, b3, W4, stD, u_lds);
        __syncthreads();
        // backward
        phaseP<512, 256, 2, 1024, 2>(tid, wd3, R1, R0, Bb, nullptr, nullptr, st2, u_lds);
        __syncthreads();
        phaseP<512, 256, 2, 1024, 2>(tid, wd2, R0, R1, Bb, nullptr, nullptr, st1, u_lds);
        __syncthreads();
        phaseP<512, 256, 2, 1024, 2>(tid, wd1, R1, R0, Bb, nullptr, nullptr, st0, u_lds);
        __syncthreads();
        phaseP<512, 128, 1, 1024, 3>(tid, wd0, R0, (char*)Zf, Bb, nullptr, nullptr, stD, u_lds);
        __syncthreads();

        // Euler / terminal (all state per-row, in regs + LDS)
        float u_reg = u_lds[em] + b4v;
        if (edg == 0 && n >= 1) { float dd = u_reg - ytil; resid += dd * dd; }
        const float* Zs = Zf + em * 132;
        if (n < NSTEP) {
            float t0v = t[grow * (NSTEP + 1) + n];
            float t1v = t[grow * (NSTEP + 1) + n + 1];
            const float* Wr0 = W + ((size_t)grow * (NSTEP + 1) + n) * DD;
            float pXZ = 0.f, pZs = 0.f;
            #pragma unroll
            for (int i = 0; i < 7; i++) {
                int d = ed0 + i;
                if (d < DD) {
                    float z = Zs[1 + d];
                    float dWv = Wr0[DD + d] - Wr0[d];
                    float s = SIGC * x[i] * dWv;
                    pXZ += x[i] * z;
                    pZs += z * s;
                    x[i] += s;
                }
            }
            pXZ += __shfl_xor(pXZ, 1); pXZ += __shfl_xor(pXZ, 2);
            pXZ += __shfl_xor(pXZ, 4); pXZ += __shfl_xor(pXZ, 8);
            pZs += __shfl_xor(pZs, 1); pZs += __shfl_xor(pZs, 2);
            pZs += __shfl_xor(pZs, 4); pZs += __shfl_xor(pZs, 8);
            if (edg == 0) {
                float phi = RC * (u_reg - pXZ);
                ytil = u_reg + phi * (t1v - t0v) + pZs;
            }
            write_tX(R1, em, edg, ed0, x, t1v);
        } else {
            float gX = 0.f, sD = 0.f;
            #pragma unroll
            for (int i = 0; i < 7; i++) {
                int d = ed0 + i;
                if (d < DD) {
                    float z = Zs[1 + d];
                    gX += x[i] * x[i];
                    float e = z - 2.f * x[i];
                    sD += e * e;
                }
            }
            gX += __shfl_xor(gX, 1); gX += __shfl_xor(gX, 2);
            gX += __shfl_xor(gX, 4); gX += __shfl_xor(gX, 8);
            sD += __shfl_xor(sD, 1); sD += __shfl_xor(sD, 2);
            sD += __shfl_xor(sD, 4); sD += __shfl_xor(sD, 8);
            if (edg == 0) {
                float e = u_reg - gX;
                resid += e * e + sD;
            }
        }
        __syncthreads();
    }

    // block-reduce resid -> one atomic per WG
    float r = resid;
    #pragma unroll
    for (int off = 1; off < 64; off <<= 1) r += __shfl_xor(r, off);
    if ((tid & 63) == 0) red[tid >> 6] = r;
    __syncthreads();
    if (tid == 0) {
        float s = 0.f;
        #pragma unroll
        for (int i = 0; i < 8; i++) s += red[i];
        atomicAdd(accG, s);
    }
}

__global__ void k_final(const float* __restrict__ acc, float* __restrict__ out) {
    out[0] = acc[0] / (float)MM;
}

// ---------- host ----------
extern "C" void kernel_launch(void* const* d_in, const int* in_sizes, int n_in,
                              void* d_out, int out_size, void* d_ws, size_t ws_size,
                              hipStream_t stream) {
    (void)in_sizes; (void)n_in; (void)out_size; (void)ws_size;
    const float* t  = (const float*)d_in[0];
    const float* W  = (const float*)d_in[1];
    const float* Xi = (const float*)d_in[2];
    const float* Wm[5];
    const float* bb[5];
    for (int i = 0; i < 5; i++) {
        Wm[i] = (const float*)d_in[3 + 2 * i];
        bb[i] = (const float*)d_in[4 + 2 * i];
    }

    char* p = (char*)d_ws;
    auto alloc = [&](size_t bytes) -> void* {
        void* r = (void*)p;
        p += (bytes + 255) & ~(size_t)255;
        return r;
    };

    __bf16* wt[4];
    wt[0] = (__bf16*)alloc((size_t)HID * K0P * 2);
    for (int i = 1; i < 4; i++) wt[i] = (__bf16*)alloc((size_t)HID * HID * 2);
    __bf16* wd[4];
    wd[0] = (__bf16*)alloc((size_t)K0P * HID * 2);
    for (int i = 1; i < 4; i++) wd[i] = (__bf16*)alloc((size_t)HID * HID * 2);
    float* acc = (float*)alloc(256);

    hipMemsetAsync(acc, 0, 256, stream);

    // weight prep: wt = W^T (N x Kpad) for fwd, wd = W (Npad x K) for bwd
    k_transpose<<<(HID * K0P + 255) / 256, 256, 0, stream>>>(Wm[0], wt[0], 101, K0P, HID);
    for (int i = 1; i < 4; i++)
        k_transpose<<<(HID * HID + 255) / 256, 256, 0, stream>>>(Wm[i], wt[i], HID, HID, HID);
    k_cast<<<(K0P * HID + 255) / 256, 256, 0, stream>>>(Wm[0], wd[0], 101, K0P, HID);
    for (int i = 1; i < 4; i++)
        k_cast<<<(HID * HID + 255) / 256, 256, 0, stream>>>(Wm[i], wd[i], HID, HID, HID);

    hipFuncSetAttribute((const void*)mega,
                        hipFuncAttributeMaxDynamicSharedMemorySize, 131328);

    mega<<<dim3(NWG), dim3(512), 131328, stream>>>(
        t, W, Xi,
        wt[0], wt[1], wt[2], wt[3],
        wd[0], wd[1], wd[2], wd[3],
        bb[0], bb[1], bb[2], bb[3],
        Wm[4], bb[4], acc);

    k_final<<<1, 1, 0, stream>>>(acc, (float*)d_out);
}

// Round 10
// 2537.668 us; speedup vs baseline: 8.1509x; 5.1827x over previous
//
#include <hip/hip_runtime.h>
#include <cstdint>
#include <cstddef>

#define MM 4096
#define NSTEP 50
#define DD 100
#define HID 512
#define K0P 128
#define SIGC 0.4f
#define RC 0.05f
#define BMR 16
#define NWG (MM / BMR)   // 256 WGs x 256 threads, one per CU

typedef __bf16 bf16x8 __attribute__((ext_vector_type(8)));
typedef float  f32x4  __attribute__((ext_vector_type(4)));
union Pack4 { __bf16 h[4]; uint2 u2; };

typedef const __attribute__((address_space(1))) void* gvp;
typedef __attribute__((address_space(3))) void* lvp;
static __device__ __forceinline__ void load_lds16(const void* g, void* l) {
    __builtin_amdgcn_global_load_lds((gvp)g, (lvp)l, 16, 0, 0);
}

template <int N>
static __device__ __forceinline__ void wait_vmcnt() {
    if constexpr (N == 0)      asm volatile("s_waitcnt vmcnt(0)" ::: "memory");
    else if constexpr (N == 4) asm volatile("s_waitcnt vmcnt(4)" ::: "memory");
    else if constexpr (N == 8) asm volatile("s_waitcnt vmcnt(8)" ::: "memory");
    __builtin_amdgcn_sched_barrier(0);
}

// ---------- weight prep (round-6 verbatim) ----------
__global__ void k_transpose(const float* __restrict__ in, __bf16* __restrict__ out,
                            int Ksrc, int Kpad, int N) {
    int idx = blockIdx.x * 256 + threadIdx.x;
    if (idx >= N * Kpad) return;
    int n = idx / Kpad, k = idx - n * Kpad;
    out[idx] = (k < Ksrc) ? (__bf16)in[k * N + n] : (__bf16)0.f;
}

__global__ void k_cast(const float* __restrict__ in, __bf16* __restrict__ out,
                       int Rsrc, int Rpad, int C) {
    int idx = blockIdx.x * 256 + threadIdx.x;
    if (idx >= Rpad * C) return;
    int r = idx / C;
    out[idx] = (r < Rsrc) ? (__bf16)in[idx] : (__bf16)0.f;
}

// ---------- init: X0 = tile(Xi), tXg row [t0, X0, 0-pad] (linear) ----------
__global__ __launch_bounds__(256) void k_init(const float* __restrict__ t,
                                              const float* __restrict__ Xi,
                                              float* __restrict__ X0,
                                              __bf16* __restrict__ tXg) {
    int m = blockIdx.x * 4 + (threadIdx.x >> 6);
    int lane = threadIdx.x & 63;
    for (int ii = 0; ii < 2; ii++) {
        int d = lane + ii * 64;
        if (d < DD) {
            float x = Xi[d];
            X0[m * DD + d] = x;
            tXg[(size_t)m * K0P + 1 + d] = (__bf16)x;
        } else if (d < K0P - 1) {
            tXg[(size_t)m * K0P + 1 + d] = (__bf16)0.f;
        }
    }
    if (lane == 0) tXg[(size_t)m * K0P] = (__bf16)t[m * (NSTEP + 1)];
}

// ---------- one layer pass (round-9-proven math, 256 threads, 3-slot pipeline) ----------
// C[m][n] = sum_k A[m][k]*B[n][k]; A: LDS swizzled [16][K]; B: streamed in
// [NBLK][64k] chunks through 3 LDS slots, counted-vmcnt + raw s_barrier.
// EPI 0: fwd: v+=bias; sin->Rout (swizzled), cos->stash regs
// EPI 1: fwd L3: v+=bias; cos*W4->Rout; u partials -> u_lds atomics
// EPI 2: bwd: v*stash -> Rout
// EPI 3: bwd L0: v f32 -> Rout as Z [16][132] f32
template <int K, int NBLK, int NJB, int ASTR, int EPI>
__device__ __forceinline__ void phaseP(
    int tid, const __bf16* __restrict__ Bw,
    const char* __restrict__ Rin, char* __restrict__ Rout, char* __restrict__ Bb,
    const float* __restrict__ bias, const float* __restrict__ W4,
    Pack4 (&stash)[2][4], float* __restrict__ u_lds) {

    constexpr int NKB = K / 64;
    constexpr int NJ  = NBLK / 64;       // 4 or 2
    constexpr int CB  = NBLK * 128;      // 32KB or 16KB
    constexpr int I   = CB / 4096;       // 8 or 4 stage instrs/thread
    constexpr int NQ  = NJB * NKB;

    const int wave = tid >> 6, lane = tid & 63;
    const int lr = lane & 15, lg = lane >> 4;
    const int am = lr;

    int bRow[I], bG[I];
    #pragma unroll
    for (int it = 0; it < I; it++) {
        int c16 = it * 256 + tid;
        bRow[it] = c16 >> 3;
        bG[it] = (c16 & 7) ^ (bRow[it] & 7);
    }

    #define STG(q)                                                              \
        {   char* dst_ = Bb + ((q) % 3) * CB + wave * 1024;                     \
            _Pragma("unroll")                                                   \
            for (int it = 0; it < I; it++)                                      \
                load_lds16(Bw + (size_t)(((q) / NKB) * NBLK + bRow[it]) * K     \
                               + ((q) % NKB) * 64 + bG[it] * 8,                 \
                           dst_ + it * 4096); }

    STG(0)
    STG(1)

    float up = 0.f;
    f32x4 acc[NJ];
    #pragma unroll
    for (int q = 0; q < NQ; q++) {
        const int jb = q / NKB, kb = q % NKB;
        if (kb == 0) {
            #pragma unroll
            for (int nj = 0; nj < NJ; nj++) acc[nj] = f32x4{0.f, 0.f, 0.f, 0.f};
        }
        if (q == NQ - 1) wait_vmcnt<0>(); else wait_vmcnt<I>();
        __builtin_amdgcn_s_barrier();       // slot q ready; prev slot reads done
        __builtin_amdgcn_sched_barrier(0);
        if (q + 2 < NQ) STG(q + 2)
        const char* slot = Bb + (q % 3) * CB;
        #pragma unroll
        for (int ks = 0; ks < 2; ks++) {
            int kch = kb * 8 + ks * 4 + lg;
            bf16x8 aF = *(const bf16x8*)(Rin + am * ASTR + ((kch ^ (am & 7)) << 4));
            #pragma unroll
            for (int nj = 0; nj < NJ; nj++) {
                int nl = wave * (NBLK / 4) + nj * 16 + lr;
                bf16x8 bF = *(const bf16x8*)(slot + nl * 128 +
                             (((ks * 4 + lg) ^ (nl & 7)) << 4));
                acc[nj] = __builtin_amdgcn_mfma_f32_16x16x32_bf16(
                    bF, aF, acc[nj], 0, 0, 0);
            }
        }
        if (kb == NKB - 1) {
            #pragma unroll
            for (int nj = 0; nj < NJ; nj++) {
                const int n0 = jb * NBLK + wave * (NBLK / 4) + nj * 16 + lg * 4;
                if (EPI == 3) {
                    *(f32x4*)((float*)Rout + am * 132 + n0) = acc[nj];
                } else {
                    const int po = am * 1024 + (((n0 >> 3) ^ (am & 7)) << 4) + (n0 & 7) * 2;
                    if (EPI == 0) {
                        f32x4 bv = *(const f32x4*)(bias + n0);
                        Pack4 ps, pc;
                        #pragma unroll
                        for (int r = 0; r < 4; r++) {
                            float s, c;
                            __sincosf(acc[nj][r] + bv[r], &s, &c);
                            ps.h[r] = (__bf16)s;
                            pc.h[r] = (__bf16)c;
                        }
                        *(uint2*)(Rout + po) = ps.u2;
                        stash[jb][nj] = pc;
                    } else if (EPI == 1) {
                        f32x4 bv = *(const f32x4*)(bias + n0);
                        f32x4 wv = *(const f32x4*)(W4 + n0);
                        Pack4 pg;
                        #pragma unroll
                        for (int r = 0; r < 4; r++) {
                            float s, c;
                            __sincosf(acc[nj][r] + bv[r], &s, &c);
                            up += s * wv[r];
                            pg.h[r] = (__bf16)(c * wv[r]);
                        }
                        *(uint2*)(Rout + po) = pg.u2;
                    } else {  // EPI == 2
                        Pack4 pm = stash[jb][nj];
                        Pack4 pg;
                        #pragma unroll
                        for (int r = 0; r < 4; r++)
                            pg.h[r] = (__bf16)(acc[nj][r] * (float)pm.h[r]);
                        *(uint2*)(Rout + po) = pg.u2;
                    }
                }
            }
        }
    }
    #undef STG

    if (EPI == 1) {
        up += __shfl_xor(up, 16);
        up += __shfl_xor(up, 32);
        if (lg == 0) atomicAdd(&u_lds[am], up);
    }
}

// ---------- per-step kernel: WG owns 16 rows, full fwd+bwd+Euler ----------
__global__ __launch_bounds__(256, 1) void mega(
    const float* __restrict__ t, const float* __restrict__ W,
    const __bf16* __restrict__ wt0, const __bf16* __restrict__ wt1,
    const __bf16* __restrict__ wt2, const __bf16* __restrict__ wt3,
    const __bf16* __restrict__ wd0, const __bf16* __restrict__ wd1,
    const __bf16* __restrict__ wd2, const __bf16* __restrict__ wd3,
    const float* __restrict__ b0, const float* __restrict__ b1,
    const float* __restrict__ b2, const float* __restrict__ b3,
    const float* __restrict__ W4, const float* __restrict__ b4,
    __bf16* __restrict__ tXg, float* __restrict__ X,
    float* __restrict__ Ytil, float* __restrict__ accG, int n) {

    extern __shared__ char lds[];
    char*  tXL   = lds;                      // 4KB  swizzled [16][256B]
    char*  R0    = lds + 4096;               // 16KB act slot
    char*  R1    = lds + 20480;              // 16KB act slot
    float* Zf    = (float*)(lds + 36864);    // [16][132] f32 = 8448B
    char*  Bb    = lds + 45312;              // 3 x 32KB chunk slots
    float* u_lds = (float*)(lds + 143616);   // 16 u + 4 red

    const int tid = threadIdx.x;
    const int wgrow = blockIdx.x * BMR;
    const int em = tid >> 4, edg = tid & 15, ed0 = edg * 7;
    const int grow = wgrow + em;
    const int lane = tid & 63, wave = tid >> 6;
    const float b4v = b4[0];

    Pack4 st0[2][4], st1[2][4], st2[2][4];

    // stage tX global(linear) -> LDS(swizzled) : 1 instr/thread
    {
        int m = tid >> 4, pc = tid & 15;
        load_lds16(tXg + (size_t)(wgrow + m) * K0P + ((pc ^ (m & 7)) << 3),
                   tXL + wave * 1024);
    }
    __syncthreads();

    // forward
    phaseP<128, 256, 2, 256, 0>(tid, wt0, tXL, R0, Bb, b0, nullptr, st0, u_lds);
    __syncthreads();
    phaseP<512, 256, 2, 1024, 0>(tid, wt1, R0, R1, Bb, b1, nullptr, st1, u_lds);
    __syncthreads();
    phaseP<512, 256, 2, 1024, 0>(tid, wt2, R1, R0, Bb, b2, nullptr, st2, u_lds);
    __syncthreads();
    if (tid < BMR) u_lds[tid] = 0.f;
    __syncthreads();
    phaseP<512, 256, 2, 1024, 1>(tid, wt3, R0, R1, Bb, b3, W4, st0 /*unused*/, u_lds);
    __syncthreads();
    // backward
    phaseP<512, 256, 2, 1024, 2>(tid, wd3, R1, R0, Bb, nullptr, nullptr, st2, u_lds);
    __syncthreads();
    phaseP<512, 256, 2, 1024, 2>(tid, wd2, R0, R1, Bb, nullptr, nullptr, st1, u_lds);
    __syncthreads();
    phaseP<512, 256, 2, 1024, 2>(tid, wd1, R1, R0, Bb, nullptr, nullptr, st0, u_lds);
    __syncthreads();
    phaseP<512, 128, 1, 1024, 3>(tid, wd0, R0, (char*)Zf, Bb, nullptr, nullptr, st0, u_lds);
    __syncthreads();

    // Euler / terminal (row-local, fp32 state in global)
    float u_reg = u_lds[em] + b4v;
    float resid_l = 0.f;
    if (n >= 1 && edg == 0) {
        float dd = u_reg - Ytil[grow];
        resid_l = dd * dd;
    }
    const float* Zs = Zf + em * 132;
    if (n < NSTEP) {
        float t0v = t[grow * (NSTEP + 1) + n];
        float t1v = t[grow * (NSTEP + 1) + n + 1];
        const float* Wr = W + ((size_t)grow * (NSTEP + 1) + n) * DD;
        float pXZ = 0.f, pZs = 0.f;
        #pragma unroll
        for (int i = 0; i < 7; i++) {
            int d = ed0 + i;
            if (d < DD) {
                float x0 = X[grow * DD + d];
                float z = Zs[1 + d];
                float dWv = Wr[DD + d] - Wr[d];
                float s = SIGC * x0 * dWv;
                pXZ += x0 * z;
                pZs += z * s;
                float x1 = x0 + s;
                X[grow * DD + d] = x1;
                tXg[(size_t)grow * K0P + 1 + d] = (__bf16)x1;
            }
        }
        pXZ += __shfl_xor(pXZ, 1); pXZ += __shfl_xor(pXZ, 2);
        pXZ += __shfl_xor(pXZ, 4); pXZ += __shfl_xor(pXZ, 8);
        pZs += __shfl_xor(pZs, 1); pZs += __shfl_xor(pZs, 2);
        pZs += __shfl_xor(pZs, 4); pZs += __shfl_xor(pZs, 8);
        if (edg == 0) {
            float phi = RC * (u_reg - pXZ);
            Ytil[grow] = u_reg + phi * (t1v - t0v) + pZs;
            tXg[(size_t)grow * K0P] = (__bf16)t1v;
        }
    } else {
        float gX = 0.f, sD = 0.f;
        #pragma unroll
        for (int i = 0; i < 7; i++) {
            int d = ed0 + i;
            if (d < DD) {
                float x0 = X[grow * DD + d];
                float z = Zs[1 + d];
                gX += x0 * x0;
                float e = z - 2.f * x0;
                sD += e * e;
            }
        }
        gX += __shfl_xor(gX, 1); gX += __shfl_xor(gX, 2);
        gX += __shfl_xor(gX, 4); gX += __shfl_xor(gX, 8);
        sD += __shfl_xor(sD, 1); sD += __shfl_xor(sD, 2);
        sD += __shfl_xor(sD, 4); sD += __shfl_xor(sD, 8);
        if (edg == 0) {
            float e = u_reg - gX;
            resid_l += e * e + sD;
        }
    }

    // reduce resid across the WG -> one atomic
    float r = resid_l;
    r += __shfl_xor(r, 16);
    r += __shfl_xor(r, 32);
    float* red = u_lds + 16;
    if (lane == 0) red[wave] = r;
    __syncthreads();
    if (tid == 0) atomicAdd(accG, red[0] + red[1] + red[2] + red[3]);
}

__global__ void k_final(const float* __restrict__ acc, float* __restrict__ out) {
    out[0] = acc[0] / (float)MM;
}

// ---------- host ----------
extern "C" void kernel_launch(void* const* d_in, const int* in_sizes, int n_in,
                              void* d_out, int out_size, void* d_ws, size_t ws_size,
                              hipStream_t stream) {
    (void)in_sizes; (void)n_in; (void)out_size; (void)ws_size;
    const float* t  = (const float*)d_in[0];
    const float* W  = (const float*)d_in[1];
    const float* Xi = (const float*)d_in[2];
    const float* Wm[5];
    const float* bb[5];
    for (int i = 0; i < 5; i++) {
        Wm[i] = (const float*)d_in[3 + 2 * i];
        bb[i] = (const float*)d_in[4 + 2 * i];
    }

    char* p = (char*)d_ws;
    auto alloc = [&](size_t bytes) -> void* {
        void* r = (void*)p;
        p += (bytes + 255) & ~(size_t)255;
        return r;
    };

    __bf16* wt[4];
    wt[0] = (__bf16*)alloc((size_t)HID * K0P * 2);
    for (int i = 1; i < 4; i++) wt[i] = (__bf16*)alloc((size_t)HID * HID * 2);
    __bf16* wd[4];
    wd[0] = (__bf16*)alloc((size_t)K0P * HID * 2);
    for (int i = 1; i < 4; i++) wd[i] = (__bf16*)alloc((size_t)HID * HID * 2);
    __bf16* tXg = (__bf16*)alloc((size_t)MM * K0P * 2);
    float* X    = (float*)alloc((size_t)MM * DD * 4);
    float* Ytil = (float*)alloc((size_t)MM * 4);
    float* acc  = (float*)alloc(256);

    hipMemsetAsync(acc, 0, 256, stream);

    // weight prep: wt = W^T (N x Kpad) fwd; wd = W (Npad x K) bwd
    k_transpose<<<(HID * K0P + 255) / 256, 256, 0, stream>>>(Wm[0], wt[0], 101, K0P, HID);
    for (int i = 1; i < 4; i++)
        k_transpose<<<(HID * HID + 255) / 256, 256, 0, stream>>>(Wm[i], wt[i], HID, HID, HID);
    k_cast<<<(K0P * HID + 255) / 256, 256, 0, stream>>>(Wm[0], wd[0], 101, K0P, HID);
    for (int i = 1; i < 4; i++)
        k_cast<<<(HID * HID + 255) / 256, 256, 0, stream>>>(Wm[i], wd[i], HID, HID, HID);

    k_init<<<MM / 4, 256, 0, stream>>>(t, Xi, X, tXg);

    const int LDSB = 143616 + 256;   // slots + u_lds/red
    hipFuncSetAttribute((const void*)mega,
                        hipFuncAttributeMaxDynamicSharedMemorySize, LDSB);

    for (int n = 0; n <= NSTEP; n++) {
        mega<<<dim3(NWG), dim3(256), LDSB, stream>>>(
            t, W,
            wt[0], wt[1], wt[2], wt[3],
            wd[0], wd[1], wd[2], wd[3],
            bb[0], bb[1], bb[2], bb[3],
            Wm[4], bb[4],
            tXg, X, Ytil, acc, n);
    }

    k_final<<<1, 1, 0, stream>>>(acc, (float*)d_out);
}

// Round 12
// 2304.329 us; speedup vs baseline: 8.9762x; 1.1013x over previous
//
#include <hip/hip_runtime.h>
#include <cstdint>
#include <cstddef>

#define MM 4096
#define NSTEP 50
#define DD 100
#define HID 512
#define K0P 128
#define SIGC 0.4f
#define RC 0.05f
#define BMR 16
#define NWG (MM / BMR)   // 256 WGs x 256 threads, one per CU

typedef __bf16 bf16x8 __attribute__((ext_vector_type(8)));
typedef float  f32x4  __attribute__((ext_vector_type(4)));
union Pack4 { __bf16 h[4]; uint2 u2; };

typedef const __attribute__((address_space(1))) void* gvp;
typedef __attribute__((address_space(3))) void* lvp;
static __device__ __forceinline__ void load_lds16(const void* g, void* l) {
    __builtin_amdgcn_global_load_lds((gvp)g, (lvp)l, 16, 0, 0);
}

template <int N>
static __device__ __forceinline__ void wait_vmcnt() {
    if constexpr (N == 0)      asm volatile("s_waitcnt vmcnt(0)" ::: "memory");
    else if constexpr (N == 4) asm volatile("s_waitcnt vmcnt(4)" ::: "memory");
    else if constexpr (N == 8) asm volatile("s_waitcnt vmcnt(8)" ::: "memory");
    __builtin_amdgcn_sched_barrier(0);
}

// ---------- weight prep (round-6 verbatim) ----------
__global__ void k_transpose(const float* __restrict__ in, __bf16* __restrict__ out,
                            int Ksrc, int Kpad, int N) {
    int idx = blockIdx.x * 256 + threadIdx.x;
    if (idx >= N * Kpad) return;
    int n = idx / Kpad, k = idx - n * Kpad;
    out[idx] = (k < Ksrc) ? (__bf16)in[k * N + n] : (__bf16)0.f;
}

__global__ void k_cast(const float* __restrict__ in, __bf16* __restrict__ out,
                       int Rsrc, int Rpad, int C) {
    int idx = blockIdx.x * 256 + threadIdx.x;
    if (idx >= Rpad * C) return;
    int r = idx / C;
    out[idx] = (r < Rsrc) ? (__bf16)in[idx] : (__bf16)0.f;
}

// ---------- init: X0 = tile(Xi), tXg row [t0, X0, 0-pad] (linear) ----------
__global__ __launch_bounds__(256) void k_init(const float* __restrict__ t,
                                              const float* __restrict__ Xi,
                                              float* __restrict__ X0,
                                              __bf16* __restrict__ tXg) {
    int m = blockIdx.x * 4 + (threadIdx.x >> 6);
    int lane = threadIdx.x & 63;
    for (int ii = 0; ii < 2; ii++) {
        int d = lane + ii * 64;
        if (d < DD) {
            float x = Xi[d];
            X0[m * DD + d] = x;
            tXg[(size_t)m * K0P + 1 + d] = (__bf16)x;
        } else if (d < K0P - 1) {
            tXg[(size_t)m * K0P + 1 + d] = (__bf16)0.f;
        }
    }
    if (lane == 0) tXg[(size_t)m * K0P] = (__bf16)t[m * (NSTEP + 1)];
}

// ---------- one layer pass: barrier-free wave-private B streaming ----------
// C[m][n] = sum_k A[m][k]*B[n][k]; A: LDS swizzled [16][K]; B: wave w streams
// ONLY its own quarter (rows [w*NBLK/4, +NBLK/4) of each [NBLK][64k] chunk)
// through 3 wave-private LDS slots; vmcnt-counted depth-2 pipeline, no barriers.
// EPI 0: fwd: v+=bias; sin->Rout (swizzled), cos->stash regs
// EPI 1: fwd L3: v+=bias; cos*W4->Rout; u partials -> u_lds atomics
// EPI 2: bwd: v*stash -> Rout
// EPI 3: bwd L0: v f32 -> Rout as Z [16][132] f32
template <int K, int NBLK, int NJB, int ASTR, int EPI>
__device__ __forceinline__ void phaseP(
    int tid, const __bf16* __restrict__ Bw,
    const char* __restrict__ Rin, char* __restrict__ Rout, char* __restrict__ Bb,
    const float* __restrict__ bias, const float* __restrict__ W4,
    Pack4 (&stash)[2][4], float* __restrict__ u_lds) {

    constexpr int NKB = K / 64;
    constexpr int NJ  = NBLK / 64;       // col frags per wave (4 or 2)
    constexpr int CB  = NBLK * 128;      // full chunk bytes (32KB or 16KB)
    constexpr int QB  = CB / 4;          // per-wave quarter bytes (8KB or 4KB)
    constexpr int I   = QB / 1024;       // per-wave stage instrs (8 or 4)
    constexpr int NQ  = NJB * NKB;

    const int wave = tid >> 6, lane = tid & 63;
    const int lr = lane & 15, lg = lane >> 4;
    const int am = lr;
    const int wrow0 = wave * (NBLK / 4);   // this wave's row base in each chunk

    // per-instr source mapping within the wave's quarter (pre-swizzled source)
    int bRow[I], bG[I];
    #pragma unroll
    for (int it = 0; it < I; it++) {
        int c16 = it * 64 + lane;          // 16B-chunk index within quarter
        bRow[it] = c16 >> 3;               // row within quarter (0..NBLK/4-1)
        bG[it]   = (c16 & 7) ^ (bRow[it] & 7);
    }

    #define STG(q)                                                              \
        {   char* dst_ = Bb + ((q) % 3) * CB + wave * QB;                       \
            _Pragma("unroll")                                                   \
            for (int it = 0; it < I; it++)                                      \
                load_lds16(Bw + (size_t)(((q) / NKB) * NBLK + wrow0 + bRow[it]) * K \
                               + ((q) % NKB) * 64 + bG[it] * 8,                 \
                           dst_ + it * 1024); }

    STG(0)
    if (NQ > 1) STG(1)

    float up = 0.f;
    f32x4 acc[NJ];
    #pragma unroll
    for (int q = 0; q < NQ; q++) {
        const int jb = q / NKB, kb = q % NKB;
        if (kb == 0) {
            #pragma unroll
            for (int nj = 0; nj < NJ; nj++) acc[nj] = f32x4{0.f, 0.f, 0.f, 0.f};
        }
        if (q + 1 < NQ) wait_vmcnt<I>(); else wait_vmcnt<0>();
        if (q + 2 < NQ) STG(q + 2)
        const char* slot = Bb + (q % 3) * CB + wave * QB;
        #pragma unroll
        for (int ks = 0; ks < 2; ks++) {
            int kch = kb * 8 + ks * 4 + lg;
            bf16x8 aF = *(const bf16x8*)(Rin + am * ASTR + ((kch ^ (am & 7)) << 4));
            #pragma unroll
            for (int nj = 0; nj < NJ; nj++) {
                int rl = nj * 16 + lr;     // row within quarter; (rl&7)==(nl&7)
                bf16x8 bF = *(const bf16x8*)(slot + rl * 128 +
                             (((ks * 4 + lg) ^ (rl & 7)) << 4));
                acc[nj] = __builtin_amdgcn_mfma_f32_16x16x32_bf16(
                    bF, aF, acc[nj], 0, 0, 0);
            }
        }
        if (kb == NKB - 1) {
            #pragma unroll
            for (int nj = 0; nj < NJ; nj++) {
                const int n0 = jb * NBLK + wrow0 + nj * 16 + lg * 4;
                if (EPI == 3) {
                    *(f32x4*)((float*)Rout + am * 132 + n0) = acc[nj];
                } else {
                    const int po = am * 1024 + (((n0 >> 3) ^ (am & 7)) << 4) + (n0 & 7) * 2;
                    if (EPI == 0) {
                        f32x4 bv = *(const f32x4*)(bias + n0);
                        Pack4 ps, pc;
                        #pragma unroll
                        for (int r = 0; r < 4; r++) {
                            float s, c;
                            __sincosf(acc[nj][r] + bv[r], &s, &c);
                            ps.h[r] = (__bf16)s;
                            pc.h[r] = (__bf16)c;
                        }
                        *(uint2*)(Rout + po) = ps.u2;
                        stash[jb][nj] = pc;
                    } else if (EPI == 1) {
                        f32x4 bv = *(const f32x4*)(bias + n0);
                        f32x4 wv = *(const f32x4*)(W4 + n0);
                        Pack4 pg;
                        #pragma unroll
                        for (int r = 0; r < 4; r++) {
                            float s, c;
                            __sincosf(acc[nj][r] + bv[r], &s, &c);
                            up += s * wv[r];
                            pg.h[r] = (__bf16)(c * wv[r]);
                        }
                        *(uint2*)(Rout + po) = pg.u2;
                    } else {  // EPI == 2
                        Pack4 pm = stash[jb][nj];
                        Pack4 pg;
                        #pragma unroll
                        for (int r = 0; r < 4; r++)
                            pg.h[r] = (__bf16)(acc[nj][r] * (float)pm.h[r]);
                        *(uint2*)(Rout + po) = pg.u2;
                    }
                }
            }
        }
    }
    #undef STG

    if (EPI == 1) {
        up += __shfl_xor(up, 16);
        up += __shfl_xor(up, 32);
        if (lg == 0) atomicAdd(&u_lds[am], up);
    }
}

// ---------- per-step kernel: WG owns 16 rows, full fwd+bwd+Euler ----------
__global__ __launch_bounds__(256, 1) void mega(
    const float* __restrict__ t, const float* __restrict__ W,
    const __bf16* __restrict__ wt0, const __bf16* __restrict__ wt1,
    const __bf16* __restrict__ wt2, const __bf16* __restrict__ wt3,
    const __bf16* __restrict__ wd0, const __bf16* __restrict__ wd1,
    const __bf16* __restrict__ wd2, const __bf16* __restrict__ wd3,
    const float* __restrict__ b0, const float* __restrict__ b1,
    const float* __restrict__ b2, const float* __restrict__ b3,
    const float* __restrict__ W4, const float* __restrict__ b4,
    __bf16* __restrict__ tXg, float* __restrict__ X,
    float* __restrict__ Ytil, float* __restrict__ accG, int n) {

    extern __shared__ char lds[];
    char*  tXL   = lds;                      // 4KB  swizzled [16][256B]
    char*  R0    = lds + 4096;               // 16KB act slot
    char*  R1    = lds + 20480;              // 16KB act slot
    float* Zf    = (float*)(lds + 36864);    // [16][132] f32 = 8448B
    char*  Bb    = lds + 45312;              // 3 x 32KB chunk slots (wave-subdivided)
    float* u_lds = (float*)(lds + 143616);   // 16 u + 4 red

    const int tid = threadIdx.x;
    const int wgrow = blockIdx.x * BMR;
    const int em = tid >> 4, edg = tid & 15, ed0 = edg * 7;
    const int grow = wgrow + em;
    const int lane = tid & 63, wave = tid >> 6;
    const float b4v = b4[0];

    Pack4 st0[2][4], st1[2][4], st2[2][4];

    // stage tX global(linear) -> LDS(swizzled) : 1 instr/thread
    {
        int m = tid >> 4, pc = tid & 15;
        load_lds16(tXg + (size_t)(wgrow + m) * K0P + ((pc ^ (m & 7)) << 3),
                   tXL + wave * 1024);
    }
    __syncthreads();

    // forward
    phaseP<128, 256, 2, 256, 0>(tid, wt0, tXL, R0, Bb, b0, nullptr, st0, u_lds);
    __syncthreads();
    phaseP<512, 256, 2, 1024, 0>(tid, wt1, R0, R1, Bb, b1, nullptr, st1, u_lds);
    __syncthreads();
    phaseP<512, 256, 2, 1024, 0>(tid, wt2, R1, R0, Bb, b2, nullptr, st2, u_lds);
    __syncthreads();
    if (tid < BMR) u_lds[tid] = 0.f;
    __syncthreads();
    phaseP<512, 256, 2, 1024, 1>(tid, wt3, R0, R1, Bb, b3, W4, st0 /*unused*/, u_lds);
    __syncthreads();
    // backward
    phaseP<512, 256, 2, 1024, 2>(tid, wd3, R1, R0, Bb, nullptr, nullptr, st2, u_lds);
    __syncthreads();
    phaseP<512, 256, 2, 1024, 2>(tid, wd2, R0, R1, Bb, nullptr, nullptr, st1, u_lds);
    __syncthreads();
    phaseP<512, 256, 2, 1024, 2>(tid, wd1, R1, R0, Bb, nullptr, nullptr, st0, u_lds);
    __syncthreads();
    phaseP<512, 128, 1, 1024, 3>(tid, wd0, R0, (char*)Zf, Bb, nullptr, nullptr, st0, u_lds);
    __syncthreads();

    // Euler / terminal (row-local, fp32 state in global)
    float u_reg = u_lds[em] + b4v;
    float resid_l = 0.f;
    if (n >= 1 && edg == 0) {
        float dd = u_reg - Ytil[grow];
        resid_l = dd * dd;
    }
    const float* Zs = Zf + em * 132;
    if (n < NSTEP) {
        float t0v = t[grow * (NSTEP + 1) + n];
        float t1v = t[grow * (NSTEP + 1) + n + 1];
        const float* Wr = W + ((size_t)grow * (NSTEP + 1) + n) * DD;
        float pXZ = 0.f, pZs = 0.f;
        #pragma unroll
        for (int i = 0; i < 7; i++) {
            int d = ed0 + i;
            if (d < DD) {
                float x0 = X[grow * DD + d];
                float z = Zs[1 + d];
                float dWv = Wr[DD + d] - Wr[d];
                float s = SIGC * x0 * dWv;
                pXZ += x0 * z;
                pZs += z * s;
                float x1 = x0 + s;
                X[grow * DD + d] = x1;
                tXg[(size_t)grow * K0P + 1 + d] = (__bf16)x1;
            }
        }
        pXZ += __shfl_xor(pXZ, 1); pXZ += __shfl_xor(pXZ, 2);
        pXZ += __shfl_xor(pXZ, 4); pXZ += __shfl_xor(pXZ, 8);
        pZs += __shfl_xor(pZs, 1); pZs += __shfl_xor(pZs, 2);
        pZs += __shfl_xor(pZs, 4); pZs += __shfl_xor(pZs, 8);
        if (edg == 0) {
            float phi = RC * (u_reg - pXZ);
            Ytil[grow] = u_reg + phi * (t1v - t0v) + pZs;
            tXg[(size_t)grow * K0P] = (__bf16)t1v;
        }
    } else {
        float gX = 0.f, sD = 0.f;
        #pragma unroll
        for (int i = 0; i < 7; i++) {
            int d = ed0 + i;
            if (d < DD) {
                float x0 = X[grow * DD + d];
                float z = Zs[1 + d];
                gX += x0 * x0;
                float e = z - 2.f * x0;
                sD += e * e;
            }
        }
        gX += __shfl_xor(gX, 1); gX += __shfl_xor(gX, 2);
        gX += __shfl_xor(gX, 4); gX += __shfl_xor(gX, 8);
        sD += __shfl_xor(sD, 1); sD += __shfl_xor(sD, 2);
        sD += __shfl_xor(sD, 4); sD += __shfl_xor(sD, 8);
        if (edg == 0) {
            float e = u_reg - gX;
            resid_l += e * e + sD;
        }
    }

    // reduce resid across the WG -> one atomic
    float r = resid_l;
    r += __shfl_xor(r, 16);
    r += __shfl_xor(r, 32);
    float* red = u_lds + 16;
    if (lane == 0) red[wave] = r;
    __syncthreads();
    if (tid == 0) atomicAdd(accG, red[0] + red[1] + red[2] + red[3]);
}

__global__ void k_final(const float* __restrict__ acc, float* __restrict__ out) {
    out[0] = acc[0] / (float)MM;
}

// ---------- host ----------
extern "C" void kernel_launch(void* const* d_in, const int* in_sizes, int n_in,
                              void* d_out, int out_size, void* d_ws, size_t ws_size,
                              hipStream_t stream) {
    (void)in_sizes; (void)n_in; (void)out_size; (void)ws_size;
    const float* t  = (const float*)d_in[0];
    const float* W  = (const float*)d_in[1];
    const float* Xi = (const float*)d_in[2];
    const float* Wm[5];
    const float* bb[5];
    for (int i = 0; i < 5; i++) {
        Wm[i] = (const float*)d_in[3 + 2 * i];
        bb[i] = (const float*)d_in[4 + 2 * i];
    }

    char* p = (char*)d_ws;
    auto alloc = [&](size_t bytes) -> void* {
        void* r = (void*)p;
        p += (bytes + 255) & ~(size_t)255;
        return r;
    };

    __bf16* wt[4];
    wt[0] = (__bf16*)alloc((size_t)HID * K0P * 2);
    for (int i = 1; i < 4; i++) wt[i] = (__bf16*)alloc((size_t)HID * HID * 2);
    __bf16* wd[4];
    wd[0] = (__bf16*)alloc((size_t)K0P * HID * 2);
    for (int i = 1; i < 4; i++) wd[i] = (__bf16*)alloc((size_t)HID * HID * 2);
    __bf16* tXg = (__bf16*)alloc((size_t)MM * K0P * 2);
    float* X    = (float*)alloc((size_t)MM * DD * 4);
    float* Ytil = (float*)alloc((size_t)MM * 4);
    float* acc  = (float*)alloc(256);

    hipMemsetAsync(acc, 0, 256, stream);

    // weight prep: wt = W^T (N x Kpad) fwd; wd = W (Npad x K) bwd
    k_transpose<<<(HID * K0P + 255) / 256, 256, 0, stream>>>(Wm[0], wt[0], 101, K0P, HID);
    for (int i = 1; i < 4; i++)
        k_transpose<<<(HID * HID + 255) / 256, 256, 0, stream>>>(Wm[i], wt[i], HID, HID, HID);
    k_cast<<<(K0P * HID + 255) / 256, 256, 0, stream>>>(Wm[0], wd[0], 101, K0P, HID);
    for (int i = 1; i < 4; i++)
        k_cast<<<(HID * HID + 255) / 256, 256, 0, stream>>>(Wm[i], wd[i], HID, HID, HID);

    k_init<<<MM / 4, 256, 0, stream>>>(t, Xi, X, tXg);

    const int LDSB = 143616 + 256;   // slots + u_lds/red
    hipFuncSetAttribute((const void*)mega,
                        hipFuncAttributeMaxDynamicSharedMemorySize, LDSB);

    for (int n = 0; n <= NSTEP; n++) {
        mega<<<dim3(NWG), dim3(256), LDSB, stream>>>(
            t, W,
            wt[0], wt[1], wt[2], wt[3],
            wd[0], wd[1], wd[2], wd[3],
            bb[0], bb[1], bb[2], bb[3],
            Wm[4], bb[4],
            tXg, X, Ytil, acc, n);
    }

    k_final<<<1, 1, 0, stream>>>(acc, (float*)d_out);
}